// Round 1
// baseline (24126.802 us; speedup 1.0000x reference)
//
#include <hip/hip_runtime.h>
#include <stddef.h>

// Elman RNN: out[t,b,u] = h_t = tanh(x_t @ Wx + h_{t-1} @ Wh + bias)
// B=128, T=512, D=128, U=512. Output [T, B, U] float32.
//
// Strategy:
//   Kernel 1 (pgemm): P[t*B+b, u] = x[b,t,:]@Wx[:,u] + bias[u], written into
//     d_out (same shape as final output). Big parallel GEMM (M=65536,K=128,N=512).
//   Kernel 2 (rnn):   one workgroup per batch row (128 WGs, no inter-WG sync).
//     Wh held REGISTER-STATIONARY: 1024 thr/WG, each thread owns a 16x16 f32
//     block of Wh (256 VGPRs). Per step: 256 reg FMAs/thread, LDS partial
//     reduce, tanh, in-place overwrite of P row with h row.

constexpr int B = 128;
constexpr int T = 512;
constexpr int D = 128;
constexpr int U = 512;

// ---------------------------------------------------------------------------
// Kernel 1: P = x @ Wx + bias   (M=T*B rows in (t,b) order, K=D, N=U)
// Tile: 128 rows x 128 cols per WG, K in 2 chunks of 64. 256 threads,
// each computes 8x8 outputs. LDS ~65 KB -> 2 WG/CU.
// ---------------------------------------------------------------------------
__global__ __launch_bounds__(256) void pgemm_kernel(
    const float* __restrict__ x,     // [B, T, D]
    const float* __restrict__ Wx,    // [D, U]
    const float* __restrict__ bias,  // [U]
    float* __restrict__ P)           // [T*B, U]  (== d_out)
{
    __shared__ float xs[128][65];    // [row][k] padded (+1) against bank conflicts
    __shared__ float ws[64][128];    // [k][col]

    const int rb  = blockIdx.x;      // 512 row blocks of 128
    const int cb  = blockIdx.y;      // 4 col blocks of 128
    const int tid = threadIdx.x;
    const int tr  = tid >> 4;        // 0..15  -> rows tr + 16*i
    const int tcc = tid & 15;        // 0..15  -> cols tcc + 16*j

    float acc[8][8];
#pragma unroll
    for (int i = 0; i < 8; ++i)
#pragma unroll
        for (int j = 0; j < 8; ++j) acc[i][j] = 0.f;

    for (int kb = 0; kb < 2; ++kb) {
        // stage x rows: row m = rb*128 + r maps to (t = m>>7, b = m&127);
        // x row address = (b*T + t)*D
#pragma unroll
        for (int l = 0; l < 32; ++l) {
            int idx = tid + l * 256;          // 0..8191
            int r   = idx >> 6;               // 0..127
            int k   = idx & 63;               // 0..63
            int m   = rb * 128 + r;
            int b_  = m & 127;
            int t_  = m >> 7;
            xs[r][k] = x[((size_t)b_ * T + t_) * D + kb * 64 + k];
        }
        // stage Wx chunk
#pragma unroll
        for (int l = 0; l < 32; ++l) {
            int idx = tid + l * 256;
            int k   = idx >> 7;               // 0..63
            int c   = idx & 127;              // 0..127
            ws[k][c] = Wx[(size_t)(kb * 64 + k) * U + cb * 128 + c];
        }
        __syncthreads();

#pragma unroll 4
        for (int k = 0; k < 64; ++k) {
            float xv[8], wv[8];
#pragma unroll
            for (int i = 0; i < 8; ++i) xv[i] = xs[tr + 16 * i][k];
#pragma unroll
            for (int j = 0; j < 8; ++j) wv[j] = ws[k][tcc + 16 * j];
#pragma unroll
            for (int i = 0; i < 8; ++i)
#pragma unroll
                for (int j = 0; j < 8; ++j)
                    acc[i][j] += xv[i] * wv[j];
        }
        __syncthreads();
    }

    // epilogue: add bias, store
#pragma unroll
    for (int j = 0; j < 8; ++j) {
        int c    = cb * 128 + tcc + 16 * j;
        float bv = bias[c];
#pragma unroll
        for (int i = 0; i < 8; ++i) {
            int m = rb * 128 + tr + 16 * i;
            P[(size_t)m * U + c] = acc[i][j] + bv;
        }
    }
}

// ---------------------------------------------------------------------------
// Kernel 2: recurrence. One WG (1024 threads) per batch row b.
//   thread layout: tk = tid>>5 (0..31) owns k in [tk*16, tk*16+16)
//                  tc = tid&31 (0..31) owns cols {tc + 32*j, j<16}
//   Wh block (16x16 f32) lives in registers for the whole kernel.
// Per step:
//   (a) prefetch P[t,b,:] (global, latency hidden under FMA phase)
//   (b) read h (16 floats via 4x float4 broadcast from LDS), 256 FMAs
//   (c) write 16 partials to part[c][tk]  (2-way bank alias = free)
//   (d) barrier; threads c<512 reduce 32 partials, tanh, store global + LDS
//   (e) barrier
// ---------------------------------------------------------------------------
__global__ __launch_bounds__(1024) void rnn_kernel(
    const float* __restrict__ Wh,    // [U, U]
    float* __restrict__ out)         // [T*B, U]; P on entry, h on exit
{
    __shared__ float h_lds[U];         // 2 KB
    __shared__ float part[U][33];      // 67.6 KB, +1 pad -> conflict-free
    const int b   = blockIdx.x;        // batch row
    const int tid = threadIdx.x;
    const int tk  = tid >> 5;          // 0..31
    const int tc  = tid & 31;          // 0..31

    // Register-stationary Wh block (coalesced load: lanes vary tc)
    float wh[16][16];
#pragma unroll
    for (int i = 0; i < 16; ++i)
#pragma unroll
        for (int j = 0; j < 16; ++j)
            wh[i][j] = Wh[(size_t)(tk * 16 + i) * U + tc + 32 * j];

    // h_0 = 0
    for (int c = tid; c < U; c += 1024) h_lds[c] = 0.f;
    __syncthreads();

    float* outb = out + (size_t)b * U;  // row (t*B + b) = outb + t*B*U

    for (int t = 0; t < T; ++t) {
        float* prow = outb + (size_t)t * B * U;

        // prefetch P value for this step (used after the mid barrier)
        float pv = 0.f;
        if (tid < U) pv = prow[tid];

        // read h fragment (broadcast: 2 distinct addresses per wave)
        float hr[16];
#pragma unroll
        for (int i = 0; i < 4; ++i) {
            float4 h4 = *reinterpret_cast<const float4*>(&h_lds[tk * 16 + i * 4]);
            hr[i * 4 + 0] = h4.x; hr[i * 4 + 1] = h4.y;
            hr[i * 4 + 2] = h4.z; hr[i * 4 + 3] = h4.w;
        }

        float acc[16];
#pragma unroll
        for (int j = 0; j < 16; ++j) acc[j] = 0.f;
#pragma unroll
        for (int i = 0; i < 16; ++i)
#pragma unroll
            for (int j = 0; j < 16; ++j)
                acc[j] += hr[i] * wh[i][j];

        // write partials: bank = (tc + tk) & 31 within wave -> <=2-way (free)
#pragma unroll
        for (int j = 0; j < 16; ++j)
            part[tc + 32 * j][tk] = acc[j];

        __syncthreads();   // partials visible

        if (tid < U) {
            float s = pv;
#pragma unroll
            for (int i = 0; i < 32; ++i) s += part[tid][i];
            float h = tanhf(s);
            prow[tid]  = h;     // overwrite P with h (final output)
            h_lds[tid] = h;     // state for next step
        }

        __syncthreads();   // h_lds visible for next step
    }
}

// ---------------------------------------------------------------------------
extern "C" void kernel_launch(void* const* d_in, const int* in_sizes, int n_in,
                              void* d_out, int out_size, void* d_ws, size_t ws_size,
                              hipStream_t stream)
{
    const float* x    = (const float*)d_in[0];  // [B, T, D]
    const float* Wx   = (const float*)d_in[1];  // [D, U]
    const float* Wh   = (const float*)d_in[2];  // [U, U]
    const float* bias = (const float*)d_in[3];  // [U]
    float* out = (float*)d_out;                 // [T, B, U]

    pgemm_kernel<<<dim3((T * B) / 128, U / 128), 256, 0, stream>>>(x, Wx, bias, out);
    rnn_kernel<<<B, 1024, 0, stream>>>(Wh, out);
}